// Round 1
// baseline (883.240 us; speedup 1.0000x reference)
//
#include <hip/hip_runtime.h>

// LSTM: B=4096, T=512, I=2, H=50, O=3.
// Design: lane = hidden unit (padded to 64), wave = 2 batch rows,
// block = 4 waves = 8 rows, 512 blocks. No __syncthreads in the T loop:
// all h/c sharing is intra-wave (wave-private LDS h row + register c).
// W_hh transposed & gate-pair-interleaved in LDS, read as ds_read_b64.

#define T_STEPS 512
#define HID     50
#define NB      2          // batch rows per wave
#define WAVES   4          // waves per block
#define BCHUNK  (WAVES*NB) // 8 rows per block

__device__ __forceinline__ float fsig(float x) {
    // 1/(1+e^{-x}) = 1/(1+2^{-x*log2 e})
    float e = __builtin_amdgcn_exp2f(-1.442695040888963f * x);
    return __builtin_amdgcn_rcpf(1.0f + e);
}
__device__ __forceinline__ float ftanh(float x) {
    // tanh(x) = 1 - 2/(e^{2x}+1),   e^{2x} = 2^{x*2*log2 e}
    float e = __builtin_amdgcn_exp2f(2.885390081777927f * x);
    return 1.0f - 2.0f * __builtin_amdgcn_rcpf(e + 1.0f);
}

__global__ __launch_bounds__(256, 2) void lstm_fused_kernel(
    const float* __restrict__ x,     // [B,T,2]
    const float* __restrict__ W_ih,  // [200,2]
    const float* __restrict__ W_hh,  // [200,50]
    const float* __restrict__ b_ih,  // [200]
    const float* __restrict__ b_hh,  // [200]
    const float* __restrict__ W_fc,  // [3,50]
    const float* __restrict__ b_fc,  // [3]
    float* __restrict__ out)         // [B,3]
{
    // wif[k*64+u] = (W_hh[u][k],     W_hh[50+u][k])   (i,f gate weights)
    // wgo[k*64+u] = (W_hh[100+u][k], W_hh[150+u][k])  (g,o gate weights)
    __shared__ float2 wif[HID * 64];
    __shared__ float2 wgo[HID * 64];
    __shared__ float  h_lds[BCHUNK * 64];   // [row][hk]

    const int tid = threadIdx.x;
    const int hk  = tid & 63;   // hidden-unit lane (50 real, 14 pad)
    const int tb  = tid >> 6;   // wave id = batch-pair id

    // ---- stage W_hh transposed (one time) ----
    for (int idx = tid; idx < HID * 64; idx += 256) {
        int k = idx >> 6;
        int u = idx & 63;
        float a0 = 0.f, a1 = 0.f, a2 = 0.f, a3 = 0.f;
        if (u < HID) {
            a0 = W_hh[(      u) * HID + k];
            a1 = W_hh[( 50 + u) * HID + k];
            a2 = W_hh[(100 + u) * HID + k];
            a3 = W_hh[(150 + u) * HID + k];
        }
        wif[idx] = make_float2(a0, a1);
        wgo[idx] = make_float2(a2, a3);
    }
    for (int idx = tid; idx < BCHUNK * 64; idx += 256) h_lds[idx] = 0.f;

    // ---- per-thread constants (bias + input weights for my 4 gates) ----
    float b4[4], wi0[4], wi1[4];
    const bool real = (hk < HID);
#pragma unroll
    for (int g = 0; g < 4; ++g) {
        int j = g * HID + (real ? hk : 0);
        b4[g]  = real ? (b_ih[j] + b_hh[j]) : 0.f;
        wi0[g] = real ? W_ih[j * 2 + 0] : 0.f;
        wi1[g] = real ? W_ih[j * 2 + 1] : 0.f;
    }

    const int b0 = blockIdx.x * BCHUNK + tb * NB;   // my first batch row
    const float* xr0 = x + (size_t)b0 * (T_STEPS * 2);
    const float* xr1 = xr0 + T_STEPS * 2;

    const int hb0 = (tb * NB + 0) * 64;
    const int hb1 = (tb * NB + 1) * 64;

    float c0 = 0.f, c1 = 0.f;

    __syncthreads();   // only barrier: W staging visible to all waves

    float2 xc0 = *(const float2*)(xr0);
    float2 xc1 = *(const float2*)(xr1);

    for (int t = 0; t < T_STEPS; ++t) {
        // prefetch next timestep's x (covers global latency under compute)
        int tn = (t + 1 < T_STEPS) ? (t + 1) : t;
        float2 xn0 = *(const float2*)(xr0 + tn * 2);
        float2 xn1 = *(const float2*)(xr1 + tn * 2);

        // gate pre-activations: bias + x contribution
        float a00 = b4[0] + xc0.x * wi0[0] + xc0.y * wi1[0];
        float a01 = b4[0] + xc1.x * wi0[0] + xc1.y * wi1[0];
        float a10 = b4[1] + xc0.x * wi0[1] + xc0.y * wi1[1];
        float a11 = b4[1] + xc1.x * wi0[1] + xc1.y * wi1[1];
        float a20 = b4[2] + xc0.x * wi0[2] + xc0.y * wi1[2];
        float a21 = b4[2] + xc1.x * wi0[2] + xc1.y * wi1[2];
        float a30 = b4[3] + xc0.x * wi0[3] + xc0.y * wi1[3];
        float a31 = b4[3] + xc1.x * wi0[3] + xc1.y * wi1[3];

        // recurrent matvec: h(t-1) . W_hh rows (4 gates x 2 rows)
#pragma unroll
        for (int k = 0; k < HID; ++k) {
            float h0 = h_lds[hb0 + k];          // broadcast read
            float h1 = h_lds[hb1 + k];          // broadcast read
            float2 vif = wif[k * 64 + hk];      // consecutive-lane b64
            float2 vgo = wgo[k * 64 + hk];
            a00 += h0 * vif.x;  a01 += h1 * vif.x;
            a10 += h0 * vif.y;  a11 += h1 * vif.y;
            a20 += h0 * vgo.x;  a21 += h1 * vgo.x;
            a30 += h0 * vgo.y;  a31 += h1 * vgo.y;
        }

        // cell update, row 0
        {
            float ig = fsig(a00), fg = fsig(a10);
            float gg = ftanh(a20), og = fsig(a30);
            c0 = fg * c0 + ig * gg;
            h_lds[hb0 + hk] = og * ftanh(c0);
        }
        // cell update, row 1
        {
            float ig = fsig(a01), fg = fsig(a11);
            float gg = ftanh(a21), og = fsig(a31);
            c1 = fg * c1 + ig * gg;
            h_lds[hb1 + hk] = og * ftanh(c1);
        }
        xc0 = xn0; xc1 = xn1;
    }

    // ---- final FC: out[b][o] = h . W_fc[o] + b_fc[o]  (O=3, tiny) ----
    if (hk < 6) {
        int r = (hk >= 3) ? 1 : 0;
        int o = hk - r * 3;
        const int hb = (tb * NB + r) * 64;
        float s = b_fc[o];
        for (int k = 0; k < HID; ++k)
            s += h_lds[hb + k] * W_fc[o * HID + k];
        out[(size_t)(b0 + r) * 3 + o] = s;
    }
}

extern "C" void kernel_launch(void* const* d_in, const int* in_sizes, int n_in,
                              void* d_out, int out_size, void* d_ws, size_t ws_size,
                              hipStream_t stream) {
    const float* x    = (const float*)d_in[0];
    const float* W_ih = (const float*)d_in[1];
    const float* W_hh = (const float*)d_in[2];
    const float* b_ih = (const float*)d_in[3];
    const float* b_hh = (const float*)d_in[4];
    const float* W_fc = (const float*)d_in[5];
    const float* b_fc = (const float*)d_in[6];
    float* out = (float*)d_out;

    dim3 grid(4096 / BCHUNK);   // 512 blocks
    dim3 block(256);
    lstm_fused_kernel<<<grid, block, 0, stream>>>(x, W_ih, W_hh, b_ih, b_hh,
                                                  W_fc, b_fc, out);
}

// Round 2
// 706.379 us; speedup vs baseline: 1.2504x; 1.2504x over previous
//
#include <hip/hip_runtime.h>

// LSTM: B=4096, T=512, I=2, H=50, O=3.
// Round 2: weights fully register-resident (200 VGPR/lane, loaded once from
// global), packed fp32 FMA (v_pk_fma_f32) pairing gates (i,f) and (g,o).
// lane = hidden unit (padded 50->64), wave = 2 batch rows, block = 4 waves,
// 512 blocks. No __syncthreads anywhere in the T loop (wave-private h rows).

typedef float v2f __attribute__((ext_vector_type(2)));

#define T_STEPS 512
#define HID     50
#define NB      2
#define WAVES   4
#define BCHUNK  (WAVES*NB)   // 8 batch rows per block

__device__ __forceinline__ float fsig(float x) {
    float e = __builtin_amdgcn_exp2f(-1.442695040888963f * x);
    return __builtin_amdgcn_rcpf(1.0f + e);
}
__device__ __forceinline__ float ftanh(float x) {
    float e = __builtin_amdgcn_exp2f(2.885390081777927f * x);
    return 1.0f - 2.0f * __builtin_amdgcn_rcpf(e + 1.0f);
}

__global__ __launch_bounds__(256, 2) void lstm_fused_kernel(
    const float* __restrict__ x,     // [B,T,2]
    const float* __restrict__ W_ih,  // [200,2]
    const float* __restrict__ W_hh,  // [200,50]
    const float* __restrict__ b_ih,  // [200]
    const float* __restrict__ b_hh,  // [200]
    const float* __restrict__ W_fc,  // [3,50]
    const float* __restrict__ b_fc,  // [3]
    float* __restrict__ out)         // [B,3]
{
    __shared__ float h_lds[BCHUNK * 64];   // [row][hk], wave-private rows

    const int tid  = threadIdx.x;
    const int hk   = tid & 63;
    const int tb   = tid >> 6;
    const bool real = (hk < HID);
    const int j    = real ? hk : 0;

    // ---- register-resident recurrent weights: wif[k]=(Wi[hk][k],Wf[hk][k]),
    //      wgo[k]=(Wg[hk][k],Wo[hk][k]); zero for pad lanes ----
    const float* Wi = W_hh + (size_t)(0 * HID + j) * HID;
    const float* Wf = W_hh + (size_t)(1 * HID + j) * HID;
    const float* Wg = W_hh + (size_t)(2 * HID + j) * HID;
    const float* Wo = W_hh + (size_t)(3 * HID + j) * HID;

    v2f wif[HID], wgo[HID];
#pragma unroll
    for (int k = 0; k < HID; ++k) {
        if (real) {
            wif[k] = (v2f){Wi[k], Wf[k]};
            wgo[k] = (v2f){Wg[k], Wo[k]};
        } else {
            wif[k] = (v2f){0.f, 0.f};
            wgo[k] = (v2f){0.f, 0.f};
        }
    }

    // biases (b_ih + b_hh) and input weights, gate-paired
    v2f bif, bgo, xw0if, xw0go, xw1if, xw1go;
    {
        int ji = 0 * HID + j, jf = 1 * HID + j, jg = 2 * HID + j, jo = 3 * HID + j;
        bif   = (v2f){b_ih[ji] + b_hh[ji], b_ih[jf] + b_hh[jf]};
        bgo   = (v2f){b_ih[jg] + b_hh[jg], b_ih[jo] + b_hh[jo]};
        xw0if = (v2f){W_ih[ji * 2 + 0], W_ih[jf * 2 + 0]};
        xw1if = (v2f){W_ih[ji * 2 + 1], W_ih[jf * 2 + 1]};
        xw0go = (v2f){W_ih[jg * 2 + 0], W_ih[jo * 2 + 0]};
        xw1go = (v2f){W_ih[jg * 2 + 1], W_ih[jo * 2 + 1]};
    }

    const int b0 = blockIdx.x * BCHUNK + tb * NB;
    const float* xr0 = x + (size_t)b0 * (T_STEPS * 2);
    const float* xr1 = xr0 + T_STEPS * 2;

    const int hb0 = (tb * NB + 0) * 64;
    const int hb1 = (tb * NB + 1) * 64;

    // zero my h entries (wave-private; no barrier needed beyond wave order)
    h_lds[hb0 + hk] = 0.f;
    h_lds[hb1 + hk] = 0.f;

    float c0 = 0.f, c1 = 0.f;

    float2 xc0 = *(const float2*)(xr0);
    float2 xc1 = *(const float2*)(xr1);

    for (int t = 0; t < T_STEPS; ++t) {
        int tn = (t + 1 < T_STEPS) ? (t + 1) : t;
        float2 xn0 = *(const float2*)(xr0 + tn * 2);
        float2 xn1 = *(const float2*)(xr1 + tn * 2);

        // gate pre-activations: bias + x contribution (packed)
        v2f aif0 = bif + xw0if * (v2f){xc0.x, xc0.x} + xw1if * (v2f){xc0.y, xc0.y};
        v2f ago0 = bgo + xw0go * (v2f){xc0.x, xc0.x} + xw1go * (v2f){xc0.y, xc0.y};
        v2f aif1 = bif + xw0if * (v2f){xc1.x, xc1.x} + xw1if * (v2f){xc1.y, xc1.y};
        v2f ago1 = bgo + xw0go * (v2f){xc1.x, xc1.x} + xw1go * (v2f){xc1.y, xc1.y};

        // recurrent matvec: weights in VGPR, h via broadcast float4 LDS reads
#pragma unroll
        for (int kk = 0; kk < 48; kk += 4) {
            float4 h0v = *(const float4*)&h_lds[hb0 + kk];
            float4 h1v = *(const float4*)&h_lds[hb1 + kk];
#pragma unroll
            for (int q = 0; q < 4; ++q) {
                float h0 = (&h0v.x)[q];
                float h1 = (&h1v.x)[q];
                aif0 += wif[kk + q] * (v2f){h0, h0};
                ago0 += wgo[kk + q] * (v2f){h0, h0};
                aif1 += wif[kk + q] * (v2f){h1, h1};
                ago1 += wgo[kk + q] * (v2f){h1, h1};
            }
        }
        {   // tail k = 48, 49
            float2 h0v = *(const float2*)&h_lds[hb0 + 48];
            float2 h1v = *(const float2*)&h_lds[hb1 + 48];
#pragma unroll
            for (int q = 0; q < 2; ++q) {
                float h0 = (&h0v.x)[q];
                float h1 = (&h1v.x)[q];
                aif0 += wif[48 + q] * (v2f){h0, h0};
                ago0 += wgo[48 + q] * (v2f){h0, h0};
                aif1 += wif[48 + q] * (v2f){h1, h1};
                ago1 += wgo[48 + q] * (v2f){h1, h1};
            }
        }

        // cell/hidden update, row 0
        {
            float ig = fsig(aif0.x), fg = fsig(aif0.y);
            float gg = ftanh(ago0.x), og = fsig(ago0.y);
            c0 = fg * c0 + ig * gg;
            h_lds[hb0 + hk] = og * ftanh(c0);
        }
        // row 1
        {
            float ig = fsig(aif1.x), fg = fsig(aif1.y);
            float gg = ftanh(ago1.x), og = fsig(ago1.y);
            c1 = fg * c1 + ig * gg;
            h_lds[hb1 + hk] = og * ftanh(c1);
        }
        xc0 = xn0; xc1 = xn1;
    }

    // ---- final FC: out[b][o] = h . W_fc[o] + b_fc[o] ----
    if (hk < 6) {
        int r = (hk >= 3) ? 1 : 0;
        int o = hk - r * 3;
        const int hb = (tb * NB + r) * 64;
        float s = b_fc[o];
        for (int k = 0; k < HID; ++k)
            s += h_lds[hb + k] * W_fc[o * HID + k];
        out[(size_t)(b0 + r) * 3 + o] = s;
    }
}

extern "C" void kernel_launch(void* const* d_in, const int* in_sizes, int n_in,
                              void* d_out, int out_size, void* d_ws, size_t ws_size,
                              hipStream_t stream) {
    const float* x    = (const float*)d_in[0];
    const float* W_ih = (const float*)d_in[1];
    const float* W_hh = (const float*)d_in[2];
    const float* b_ih = (const float*)d_in[3];
    const float* b_hh = (const float*)d_in[4];
    const float* W_fc = (const float*)d_in[5];
    const float* b_fc = (const float*)d_in[6];
    float* out = (float*)d_out;

    dim3 grid(4096 / BCHUNK);   // 512 blocks
    dim3 block(256);
    lstm_fused_kernel<<<grid, block, 0, stream>>>(x, W_ih, W_hh, b_ih, b_hh,
                                                  W_fc, b_fc, out);
}